// Round 14
// baseline (47.495 us; speedup 1.0000x reference)
//
#include <hip/hip_runtime.h>
#include <math.h>

// B=4, C=64, H=W=128, OUTC=64, KS=3, taps N=9, K = 9*64 = 576. All fp16 data, f32 accum.
// ws layout (bytes):
//   x_t   fp16 [4][128][128][64]   @ 0        (8 MB) NHWC
//   cwtf  fp16 [9][2][4][64][8]    @ 8388608  (72 KB) main-conv B-fragments
//   pwtf  fp16 [9][2][2][64][8]    @ 8462336  (36 KB) offset-conv B-fragments (rows>=18 zero)
#define CWTF_OFF 8388608
#define PWTF_OFF (CWTF_OFF + 73728)

typedef __attribute__((ext_vector_type(8))) _Float16 half8;
typedef __attribute__((ext_vector_type(8))) unsigned short ushort8;
typedef __attribute__((ext_vector_type(4))) float f32x4;
typedef __attribute__((ext_vector_type(4))) unsigned int u32x4;

__device__ inline unsigned short f2h(float f) {
    _Float16 h = (_Float16)f; return __builtin_bit_cast(unsigned short, h);
}

// ---------------- prep: x NCHW f32 -> NHWC fp16, + weights -> fragment order ----------------
__global__ __launch_bounds__(256) void k_prep(const float* __restrict__ x,
                                              unsigned int* __restrict__ x_t_u32,
                                              const float* __restrict__ conv_w,
                                              const float* __restrict__ p_w,
                                              unsigned short* __restrict__ cwtf,
                                              unsigned short* __restrict__ pwtf) {
    if (blockIdx.x < 512) {
        __shared__ float t[64][129];
        int b = blockIdx.x >> 7;
        int i = blockIdx.x & 127;
        for (int idx = threadIdx.x; idx < 64 * 128; idx += 256) {
            int c = idx >> 7, j = idx & 127;
            t[c][j] = x[(((size_t)(b * 64 + c) * 128 + i) << 7) + j];
        }
        __syncthreads();
        unsigned int* dst = x_t_u32 + ((size_t)(b * 128 + i)) * 128 * 32;
        for (int idx2 = threadIdx.x; idx2 < 4096; idx2 += 256) {
            int j = idx2 >> 5, c2 = idx2 & 31;
            unsigned int lo = f2h(t[2 * c2][j]);
            unsigned int hi = f2h(t[2 * c2 + 1][j]);
            dst[idx2] = lo | (hi << 16);
        }
    } else {
        int tid = (blockIdx.x - 512) * 256 + threadIdx.x;
        if (tid < 36864) {
            int e = tid & 7, lane = (tid >> 3) & 63, nb = (tid >> 9) & 3, h = (tid >> 11) & 1, n = tid >> 12;
            int o = nb * 16 + (lane & 15);
            int c = h * 32 + ((lane >> 4) << 3) + e;
            cwtf[tid] = f2h(conv_w[(o * 64 + c) * 9 + n]);
        } else if (tid < 36864 + 18432) {
            int t2 = tid - 36864;
            int e = t2 & 7, lane = (t2 >> 3) & 63, nb = (t2 >> 9) & 1, h = (t2 >> 10) & 1, n = t2 >> 11;
            int np = nb * 16 + (lane & 15);
            int c = h * 32 + ((lane >> 4) << 3) + e;
            pwtf[t2] = (np < 18) ? f2h(p_w[(np * 64 + c) * 9 + n]) : (unsigned short)0;
        }
    }
}

// ---------------- fused kernel (r11 base; phase-1 A from global; 5 barriers) ----------------
// Block = 64 pixels (b, i, j0..j0+63), 8 waves (512 thr): wave wv = (pg = wv&3, h = wv>>2).
// Phase 1 reads A directly from x_t (global) -> independent of tile staging; staging DMA
// drains under phase-1 compute and is covered by the same barrier as the offs writes.
// Cross-h reduce via disjoint offs0/offs1 (offs1 overlays geom; geom written post-barrier).
// MFMA 16x16x32 f16: A m=lane&15, k=8*(lane>>4)+e; B n=lane&15 same k; D n=lane&15, m=4*(lane>>4)+reg.
#define TROWS 7
#define TCOLS 71
#define TRECS (TROWS * TCOLS)      // 497 records of 128 B (64 ch fp16)
#define TILE_B (TRECS * 128)       // 63616 B
#define OFF_OFFS TILE_B            // 4608 B  [64][18] f32 (h=0 half)
#define OFF_GEOM (TILE_B + 4608)   // 9216 B  [9][64][4] packed u32; first 4608 B double as offs1
#define OFF_FLAG (TILE_B + 4608 + 9216)
// Epilogue: ep0 @ 0, ep1 @ 16640 ([64][65] f32 each) overlay the dead tile.

__global__ __launch_bounds__(512, 2) void k_fused(const unsigned short* __restrict__ x_t,
                                                  const unsigned short* __restrict__ cwtf,
                                                  const unsigned short* __restrict__ pwtf,
                                                  const float* __restrict__ p_b,
                                                  const float* __restrict__ conv_b,
                                                  float* __restrict__ out) {
    __shared__ __align__(16) unsigned char S[TILE_B + 4608 + 9216 + 16];
    unsigned char* tile = S;
    float* offs0 = (float*)(S + OFF_OFFS);
    float* offs1 = (float*)(S + OFF_GEOM);   // overlays geom; dead once geom is written
    unsigned char* geomB = S + OFF_GEOM;
    int* flagp = (int*)(S + OFF_FLAG);

    int bid0 = blockIdx.x;
    int bid = (bid0 & 7) * 128 + (bid0 >> 3);  // chunked XCD swizzle (1024 % 8 == 0)
    int b = bid >> 8;
    int i = (bid >> 1) & 127;
    int j0 = (bid & 1) << 6;
    int ib = i - 3, jb = j0 - 3;

    int tid = threadIdx.x;
    int lane = tid & 63;
    int r15 = lane & 15;
    int g = lane >> 4;
    int wv = tid >> 6;
    int pg = wv & 3;
    int h = wv >> 2;
    int pl = pg * 16 + r15;      // this lane's A-row pixel
    int cs = g + (h << 2);       // chunk slot: channels cs*8..cs*8+7

    if (tid == 0) *flagp = 0;

    // ---- stage swizzled x-tile (coalesced global, swizzled ds_write); drains under phase 1 ----
    for (int u = tid; u < TRECS * 8; u += 512) {
        int rec = u >> 3, chunk = u & 7;
        int trow = rec / TCOLS;
        int tcol = rec - trow * TCOLS;
        int gr = ib + trow, gc = jb + tcol;
        bool v = ((unsigned)gr < 128u) && ((unsigned)gc < 128u);
        int grc = v ? gr : 0, gcc = v ? gc : 0;
        ushort8 val = *(const ushort8*)(x_t + (((size_t)((b * 128 + grc) * 128 + gcc)) << 6) + (chunk << 3));
        if (!v) val = (ushort8)(unsigned short)0;
        *(ushort8*)(tile + rec * 128 + ((chunk ^ (rec & 7)) << 4)) = val;
    }

    // ---- phase 1: offset conv — A direct from GLOBAL x_t (no staging dependency) ----
    f32x4 aco0 = (f32x4)0.f, aco1 = (f32x4)0.f;
#pragma unroll 3
    for (int n = 0; n < 9; ++n) {
        int du = n / 3 - 1, dv = n % 3 - 1;
        int row = i + du;
        int col = j0 + pl + dv;
        bool valid = ((unsigned)row < 128u) && ((unsigned)col < 128u);
        int rowc = valid ? row : 0;
        int colc = valid ? col : 0;
        ushort8 araw = *(const ushort8*)(x_t + (((size_t)((b * 128 + rowc) * 128 + colc)) << 6) + (cs << 3));
        if (!valid) araw = (ushort8)(unsigned short)0;
        half8 a = __builtin_bit_cast(half8, araw);
        const unsigned short* pb = pwtf + (((n * 2 + h) * 2) << 9) + (lane << 3);
        half8 b0 = *(const half8*)pb;
        half8 b1 = *(const half8*)(pb + 512);
        aco0 = __builtin_amdgcn_mfma_f32_16x16x32_f16(a, b0, aco0, 0, 0, 0);
        aco1 = __builtin_amdgcn_mfma_f32_16x16x32_f16(a, b1, aco1, 0, 0, 0);
    }
    // concurrent disjoint writes: h=0 -> offs0 (+bias), h=1 -> offs1
    {
        float* offsH = h ? offs1 : offs0;
#pragma unroll
        for (int nb = 0; nb < 2; ++nb) {
            int np = nb * 16 + r15;
            if (np < 18) {
                f32x4 a = nb ? aco1 : aco0;
                float bias = h ? 0.f : p_b[np];
#pragma unroll
                for (int rr = 0; rr < 4; ++rr) {
                    int pix = pg * 16 + g * 4 + rr;
                    offsH[pix * 18 + np] = a[rr] + bias;
                }
            }
        }
    }
    __syncthreads();  // covers staging ds_writes AND offs0/offs1

    // ---- phase 2: bilinear geometry (reg-staged reads; overlay-write geom after barrier) ----
    u32x4 gA, gB;
    bool badA = false, badB = false;
#pragma unroll
    for (int pass = 0; pass < 2; ++pass) {
        if (pass == 1 && tid >= 64) break;
        int m = tid + pass * 512;
        int n = m >> 6, p = m & 63;
        float ox = offs0[p * 18 + n] + offs1[p * 18 + n];
        float oy = offs0[p * 18 + 9 + n] + offs1[p * 18 + 9 + n];
        float px = ox + (float)(i + 1) + (float)(n / 3 - 1);
        float py = oy + (float)(j0 + p + 1) + (float)(n % 3 - 1);
        float fx = floorf(px), fy = floorf(py);
        float qlx = fminf(fmaxf(fx, 0.f), 129.f);
        float qrx = fminf(fmaxf(fx + 1.f, 0.f), 129.f);
        float qly = fminf(fmaxf(fy, 0.f), 129.f);
        float qry = fminf(fmaxf(fy + 1.f, 0.f), 129.f);
        float pxc = fminf(fmaxf(px, 0.f), 129.f);
        float pyc = fminf(fmaxf(py, 0.f), 129.f);
        float ax = 1.f + qlx - pxc;
        float bx = 1.f - qrx + pxc;
        float ay = 1.f + qly - pyc;
        float by = 1.f - qry + pyc;
        int rlx = (int)qlx - 1, rrx = (int)qrx - 1;
        int rly = (int)qly - 1, rry = (int)qry - 1;
        int cx[4] = {rlx, rrx, rlx, rrx};
        int cy[4] = {rly, rry, rry, rly};
        float cw[4] = {ax * ay, bx * by, ax * by, bx * ay};
        u32x4 pk;
        bool bad = false;
#pragma unroll
        for (int k = 0; k < 4; ++k) {
            bool v = ((unsigned)cx[k] < 128u) && ((unsigned)cy[k] < 128u);
            bool intile = (((unsigned)(cx[k] - ib) < (unsigned)TROWS) &&
                           ((unsigned)(cy[k] - jb) < (unsigned)TCOLS));
            pk[k] = v ? (0x80000000u | ((unsigned)cx[k] << 23) | ((unsigned)cy[k] << 16) | f2h(cw[k])) : 0u;
            bad = bad || (v && !intile);
        }
        if (pass == 0) { gA = pk; badA = bad; } else { gB = pk; badB = bad; }
    }
    __syncthreads();  // offs reads complete; safe to overlay geom
    *(u32x4*)(geomB + (tid << 4)) = gA;   // item index m == n*64+p
    if (tid < 64) *(u32x4*)(geomB + ((tid + 512) << 4)) = gB;
    if (badA || badB) *flagp = 1;
    __syncthreads();

    // ---- phase 3: main conv — fp16 packed bilinear, wave handles its k-half ----
    f32x4 acc[4];
#pragma unroll
    for (int nb = 0; nb < 4; ++nb) acc[nb] = (f32x4)0.f;
    bool fast = (*flagp == 0);

    if (fast) {
        for (int n = 0; n < 9; ++n) {
            u32x4 gq = *(const u32x4*)(geomB + ((n * 64 + pl) << 4));
            half8 Bf[4];
#pragma unroll
            for (int nb = 0; nb < 4; ++nb)
                Bf[nb] = *(const half8*)(cwtf + ((((n * 2 + h) << 2) + nb) << 9) + (lane << 3));
            half8 av = (half8)(_Float16)0;
#pragma unroll
            for (int k = 0; k < 4; ++k) {
                unsigned int p = gq[k];
                int rx = (int)((p >> 23) & 127u), ry = (int)((p >> 16) & 127u);
                int trec = (rx - ib) * TCOLS + (ry - jb);
                if (p == 0u) trec = 0;
                _Float16 wk = __builtin_bit_cast(_Float16, (unsigned short)(p & 0xFFFFu));
                int xb = trec & 7;
                half8 u = *(const half8*)(tile + trec * 128 + ((cs ^ xb) << 4));
                av += u * wk;   // v_pk_fma_f16
            }
#pragma unroll
            for (int nb = 0; nb < 4; ++nb)
                acc[nb] = __builtin_amdgcn_mfma_f32_16x16x32_f16(av, Bf[nb], acc[nb], 0, 0, 0);
        }
    } else {
        for (int n = 0; n < 9; ++n) {
            u32x4 gq = *(const u32x4*)(geomB + ((n * 64 + pl) << 4));
            half8 Bf[4];
#pragma unroll
            for (int nb = 0; nb < 4; ++nb)
                Bf[nb] = *(const half8*)(cwtf + ((((n * 2 + h) << 2) + nb) << 9) + (lane << 3));
            half8 av = (half8)(_Float16)0;
#pragma unroll
            for (int k = 0; k < 4; ++k) {
                unsigned int p = gq[k];
                int rx = (int)((p >> 23) & 127u), ry = (int)((p >> 16) & 127u);
                size_t base = (p == 0u) ? 0 : (((size_t)((b * 128 + rx) * 128 + ry)) << 6);
                _Float16 wk = __builtin_bit_cast(_Float16, (unsigned short)(p & 0xFFFFu));
                half8 u = *(const half8*)(x_t + base + (cs << 3));
                av += u * wk;
            }
#pragma unroll
            for (int nb = 0; nb < 4; ++nb)
                acc[nb] = __builtin_amdgcn_mfma_f32_16x16x32_f16(av, Bf[nb], acc[nb], 0, 0, 0);
        }
    }
    __syncthreads();  // tile dead; reuse as ep0/ep1

    // ---- epilogue: disjoint per-half regions, ONE barrier, summed at store ----
    {
        float* epH = (float*)(S + (h ? 16640 : 0));
#pragma unroll
        for (int nb = 0; nb < 4; ++nb) {
            int o = nb * 16 + r15;
#pragma unroll
            for (int rr = 0; rr < 4; ++rr) {
                int pix = pg * 16 + g * 4 + rr;
                epH[o * 65 + pix] = acc[nb][rr];
            }
        }
    }
    __syncthreads();
    {
        float* e0 = (float*)S;
        float* e1 = (float*)(S + 16640);
        for (int t = tid; t < 4096; t += 512) {
            int o = t >> 6;
            int p = t & 63;
            out[(((size_t)(b * 64 + o)) << 14) + (i << 7) + j0 + p] =
                e0[o * 65 + p] + e1[o * 65 + p] + conv_b[o];
        }
    }
}

extern "C" void kernel_launch(void* const* d_in, const int* in_sizes, int n_in,
                              void* d_out, int out_size, void* d_ws, size_t ws_size,
                              hipStream_t stream) {
    const float* x = (const float*)d_in[0];
    const float* p_w = (const float*)d_in[1];
    const float* p_b = (const float*)d_in[2];
    const float* conv_w = (const float*)d_in[3];
    const float* conv_b = (const float*)d_in[4];
    float* out = (float*)d_out;
    char* ws = (char*)d_ws;

    unsigned short* x_t = (unsigned short*)(ws);
    unsigned short* cwtf = (unsigned short*)(ws + CWTF_OFF);
    unsigned short* pwtf = (unsigned short*)(ws + PWTF_OFF);

    k_prep<<<728, 256, 0, stream>>>(x, (unsigned int*)x_t, conv_w, p_w, cwtf, pwtf);
    k_fused<<<1024, 512, 0, stream>>>(x_t, cwtf, pwtf, p_b, conv_b, out);
}

// Round 15
// 43.350 us; speedup vs baseline: 1.0956x; 1.0956x over previous
//
#include <hip/hip_runtime.h>
#include <math.h>

// B=4, C=64, H=W=128, OUTC=64, KS=3, taps N=9, K = 9*64 = 576. All fp16 data, f32 accum.
// ws layout (bytes):
//   x_t   fp16 [4][128][128][64]   @ 0        (8 MB) NHWC
//   cwtf  fp16 [9][2][4][64][8]    @ 8388608  (72 KB) main-conv B-fragments
//   pwtf  fp16 [9][2][2][64][8]    @ 8462336  (36 KB) offset-conv B-fragments (rows>=18 zero)
#define CWTF_OFF 8388608
#define PWTF_OFF (CWTF_OFF + 73728)

typedef __attribute__((ext_vector_type(8))) _Float16 half8;
typedef __attribute__((ext_vector_type(8))) unsigned short ushort8;
typedef __attribute__((ext_vector_type(4))) float f32x4;
typedef __attribute__((ext_vector_type(4))) unsigned int u32x4;

__device__ inline unsigned short f2h(float f) {
    _Float16 h = (_Float16)f; return __builtin_bit_cast(unsigned short, h);
}

// ---------------- prep: x NCHW f32 -> NHWC fp16 (half-row blocks), + weights -> fragment order ----------------
// Blocks 0..1023: transpose half-row (b, i, j-half): 64 ch x 64 j. LDS 16.6 KB -> high occupancy.
// Blocks 1024..1239: weight fragment packing (identical logic to prior rounds).
__global__ __launch_bounds__(256) void k_prep(const float* __restrict__ x,
                                              unsigned int* __restrict__ x_t_u32,
                                              const float* __restrict__ conv_w,
                                              const float* __restrict__ p_w,
                                              unsigned short* __restrict__ cwtf,
                                              unsigned short* __restrict__ pwtf) {
    if (blockIdx.x < 1024) {
        __shared__ float t[64][65];
        int blk = blockIdx.x;
        int b = blk >> 8;
        int i = (blk >> 1) & 127;
        int j0 = (blk & 1) << 6;
        // load: 16 coalesced f32 per thread (consecutive tid -> consecutive j)
        for (int idx = threadIdx.x; idx < 4096; idx += 256) {
            int c = idx >> 6, jj = idx & 63;
            t[c][jj] = x[(((size_t)(b * 64 + c) * 128 + i) << 7) + j0 + jj];
        }
        __syncthreads();
        // store: 8 coalesced u32 per thread (consecutive tid -> consecutive c2)
        unsigned int* dst = x_t_u32 + (((size_t)(b * 128 + i)) * 128 + j0) * 32;
        for (int idx2 = threadIdx.x; idx2 < 2048; idx2 += 256) {
            int jj = idx2 >> 5, c2 = idx2 & 31;
            unsigned int lo = f2h(t[2 * c2][jj]);
            unsigned int hi = f2h(t[2 * c2 + 1][jj]);
            dst[(size_t)jj * 32 + c2] = lo | (hi << 16);
        }
    } else {
        int tid = (blockIdx.x - 1024) * 256 + threadIdx.x;
        if (tid < 36864) {
            int e = tid & 7, lane = (tid >> 3) & 63, nb = (tid >> 9) & 3, h = (tid >> 11) & 1, n = tid >> 12;
            int o = nb * 16 + (lane & 15);
            int c = h * 32 + ((lane >> 4) << 3) + e;
            cwtf[tid] = f2h(conv_w[(o * 64 + c) * 9 + n]);
        } else if (tid < 36864 + 18432) {
            int t2 = tid - 36864;
            int e = t2 & 7, lane = (t2 >> 3) & 63, nb = (t2 >> 9) & 1, h = (t2 >> 10) & 1, n = t2 >> 11;
            int np = nb * 16 + (lane & 15);
            int c = h * 32 + ((lane >> 4) << 3) + e;
            pwtf[t2] = (np < 18) ? f2h(p_w[(np * 64 + c) * 9 + n]) : (unsigned short)0;
        }
    }
}

// ---------------- fused kernel (r11, verbatim) ----------------
// Block = 64 pixels (b, i, j0..j0+63), 8 waves (512 thr): wave wv = (pg = wv&3, h = wv>>2).
// Tile margin 3: covers |offset| < 2 (8 sigma) -> slow path statistically never taken.
// MFMA 16x16x32 f16: A m=lane&15, k=8*(lane>>4)+e; B n=lane&15 same k; D n=lane&15, m=4*(lane>>4)+reg.
#define TROWS 7
#define TCOLS 71
#define TRECS (TROWS * TCOLS)      // 497 records of 128 B (64 ch fp16)
#define TILE_B (TRECS * 128)       // 63616 B
#define OFF_OFFS TILE_B            // 4608 B  [64][18] f32
#define OFF_GEOM (TILE_B + 4608)   // 9216 B  [9][64][4] packed u32
#define OFF_FLAG (TILE_B + 4608 + 9216)
// Epilogue: ep0 @ 0, ep1 @ 16640 ([64][65] f32 each) overlay the dead tile.

__global__ __launch_bounds__(512, 2) void k_fused(const unsigned short* __restrict__ x_t,
                                                  const unsigned short* __restrict__ cwtf,
                                                  const unsigned short* __restrict__ pwtf,
                                                  const float* __restrict__ p_b,
                                                  const float* __restrict__ conv_b,
                                                  float* __restrict__ out) {
    __shared__ __align__(16) unsigned char S[TILE_B + 4608 + 9216 + 16];
    unsigned char* tile = S;
    float* offs = (float*)(S + OFF_OFFS);
    unsigned char* geomB = S + OFF_GEOM;
    int* flagp = (int*)(S + OFF_FLAG);

    int bid0 = blockIdx.x;
    int bid = (bid0 & 7) * 128 + (bid0 >> 3);  // chunked XCD swizzle (1024 % 8 == 0)
    int b = bid >> 8;
    int i = (bid >> 1) & 127;
    int j0 = (bid & 1) << 6;
    int ib = i - 3, jb = j0 - 3;

    int tid = threadIdx.x;
    int lane = tid & 63;
    int r15 = lane & 15;
    int g = lane >> 4;
    int wv = tid >> 6;
    int pg = wv & 3;
    int h = wv >> 2;
    int pl = pg * 16 + r15;      // this lane's A-row pixel
    int cs = g + (h << 2);       // chunk slot: channels cs*8..cs*8+7

    if (tid == 0) *flagp = 0;

    // ---- stage swizzled x-tile (coalesced global, swizzled ds_write) ----
    for (int u = tid; u < TRECS * 8; u += 512) {
        int rec = u >> 3, chunk = u & 7;
        int trow = rec / TCOLS;
        int tcol = rec - trow * TCOLS;
        int gr = ib + trow, gc = jb + tcol;
        bool v = ((unsigned)gr < 128u) && ((unsigned)gc < 128u);
        int grc = v ? gr : 0, gcc = v ? gc : 0;
        ushort8 val = *(const ushort8*)(x_t + (((size_t)((b * 128 + grc) * 128 + gcc)) << 6) + (chunk << 3));
        if (!v) val = (ushort8)(unsigned short)0;
        *(ushort8*)(tile + rec * 128 + ((chunk ^ (rec & 7)) << 4)) = val;
    }
    __syncthreads();

    // ---- phase 1: offset conv — wave supplies its channel-half's k-block ----
    f32x4 aco0 = (f32x4)0.f, aco1 = (f32x4)0.f;
    for (int n = 0; n < 9; ++n) {
        int du = n / 3 - 1, dv = n % 3 - 1;
        int trec = (du + 3) * TCOLS + (pl + dv + 3);
        int xb = trec & 7;
        half8 a = *(const half8*)(tile + trec * 128 + ((cs ^ xb) << 4));
        const unsigned short* pb = pwtf + (((n * 2 + h) * 2) << 9) + (lane << 3);
        half8 b0 = *(const half8*)pb;
        half8 b1 = *(const half8*)(pb + 512);
        aco0 = __builtin_amdgcn_mfma_f32_16x16x32_f16(a, b0, aco0, 0, 0, 0);
        aco1 = __builtin_amdgcn_mfma_f32_16x16x32_f16(a, b1, aco1, 0, 0, 0);
    }
    // cross-h reduction of offsets: h=0 writes (+bias), h=1 adds
#pragma unroll
    for (int hh = 0; hh < 2; ++hh) {
        if (h == hh) {
#pragma unroll
            for (int nb = 0; nb < 2; ++nb) {
                int np = nb * 16 + r15;
                if (np < 18) {
                    f32x4 a = nb ? aco1 : aco0;
#pragma unroll
                    for (int rr = 0; rr < 4; ++rr) {
                        int pix = pg * 16 + g * 4 + rr;
                        if (hh == 0)
                            offs[pix * 18 + np] = a[rr] + p_b[np];
                        else
                            offs[pix * 18 + np] += a[rr];
                    }
                }
            }
        }
        __syncthreads();
    }

    // ---- phase 2: bilinear geometry, packed (validbit|rx|ry|f16 w) ----
    for (int t = tid; t < 576; t += 512) {
        int p = t / 9;
        int n = t - p * 9;
        float ox = offs[p * 18 + n];
        float oy = offs[p * 18 + 9 + n];
        float px = ox + (float)(i + 1) + (float)(n / 3 - 1);
        float py = oy + (float)(j0 + p + 1) + (float)(n % 3 - 1);
        float fx = floorf(px), fy = floorf(py);
        float qlx = fminf(fmaxf(fx, 0.f), 129.f);
        float qrx = fminf(fmaxf(fx + 1.f, 0.f), 129.f);
        float qly = fminf(fmaxf(fy, 0.f), 129.f);
        float qry = fminf(fmaxf(fy + 1.f, 0.f), 129.f);
        float pxc = fminf(fmaxf(px, 0.f), 129.f);
        float pyc = fminf(fmaxf(py, 0.f), 129.f);
        float ax = 1.f + qlx - pxc;
        float bx = 1.f - qrx + pxc;
        float ay = 1.f + qly - pyc;
        float by = 1.f - qry + pyc;
        int rlx = (int)qlx - 1, rrx = (int)qrx - 1;
        int rly = (int)qly - 1, rry = (int)qry - 1;
        bool bad = false;
        unsigned int pk[4];
        int cx[4] = {rlx, rrx, rlx, rrx};
        int cy[4] = {rly, rry, rry, rly};
        float cw[4] = {ax * ay, bx * by, ax * by, bx * ay};
#pragma unroll
        for (int k = 0; k < 4; ++k) {
            bool v = ((unsigned)cx[k] < 128u) && ((unsigned)cy[k] < 128u);
            bool intile = (((unsigned)(cx[k] - ib) < (unsigned)TROWS) &&
                           ((unsigned)(cy[k] - jb) < (unsigned)TCOLS));
            pk[k] = v ? (0x80000000u | ((unsigned)cx[k] << 23) | ((unsigned)cy[k] << 16) | f2h(cw[k])) : 0u;
            bad = bad || (v && !intile);
        }
        *(u32x4*)(geomB + ((n * 64 + p) << 4)) = (u32x4){pk[0], pk[1], pk[2], pk[3]};
        if (bad) *flagp = 1;
    }
    __syncthreads();

    // ---- phase 3: main conv — fp16 packed bilinear, wave handles its k-half ----
    f32x4 acc[4];
#pragma unroll
    for (int nb = 0; nb < 4; ++nb) acc[nb] = (f32x4)0.f;
    bool fast = (*flagp == 0);

    if (fast) {
        for (int n = 0; n < 9; ++n) {
            u32x4 gq = *(const u32x4*)(geomB + ((n * 64 + pl) << 4));
            half8 Bf[4];
#pragma unroll
            for (int nb = 0; nb < 4; ++nb)
                Bf[nb] = *(const half8*)(cwtf + ((((n * 2 + h) << 2) + nb) << 9) + (lane << 3));
            half8 av = (half8)(_Float16)0;
#pragma unroll
            for (int k = 0; k < 4; ++k) {
                unsigned int p = gq[k];
                int rx = (int)((p >> 23) & 127u), ry = (int)((p >> 16) & 127u);
                int trec = (rx - ib) * TCOLS + (ry - jb);
                if (p == 0u) trec = 0;
                _Float16 wk = __builtin_bit_cast(_Float16, (unsigned short)(p & 0xFFFFu));
                int xb = trec & 7;
                half8 u = *(const half8*)(tile + trec * 128 + ((cs ^ xb) << 4));
                av += u * wk;   // v_pk_fma_f16
            }
#pragma unroll
            for (int nb = 0; nb < 4; ++nb)
                acc[nb] = __builtin_amdgcn_mfma_f32_16x16x32_f16(av, Bf[nb], acc[nb], 0, 0, 0);
        }
    } else {
        for (int n = 0; n < 9; ++n) {
            u32x4 gq = *(const u32x4*)(geomB + ((n * 64 + pl) << 4));
            half8 Bf[4];
#pragma unroll
            for (int nb = 0; nb < 4; ++nb)
                Bf[nb] = *(const half8*)(cwtf + ((((n * 2 + h) << 2) + nb) << 9) + (lane << 3));
            half8 av = (half8)(_Float16)0;
#pragma unroll
            for (int k = 0; k < 4; ++k) {
                unsigned int p = gq[k];
                int rx = (int)((p >> 23) & 127u), ry = (int)((p >> 16) & 127u);
                size_t base = (p == 0u) ? 0 : (((size_t)((b * 128 + rx) * 128 + ry)) << 6);
                _Float16 wk = __builtin_bit_cast(_Float16, (unsigned short)(p & 0xFFFFu));
                half8 u = *(const half8*)(x_t + base + (cs << 3));
                av += u * wk;
            }
#pragma unroll
            for (int nb = 0; nb < 4; ++nb)
                acc[nb] = __builtin_amdgcn_mfma_f32_16x16x32_f16(av, Bf[nb], acc[nb], 0, 0, 0);
        }
    }
    __syncthreads();  // tile dead; reuse as ep0/ep1

    // ---- epilogue: disjoint per-half regions, ONE barrier, summed at store ----
    {
        float* epH = (float*)(S + (h ? 16640 : 0));
#pragma unroll
        for (int nb = 0; nb < 4; ++nb) {
            int o = nb * 16 + r15;
#pragma unroll
            for (int rr = 0; rr < 4; ++rr) {
                int pix = pg * 16 + g * 4 + rr;
                epH[o * 65 + pix] = acc[nb][rr];
            }
        }
    }
    __syncthreads();
    {
        float* e0 = (float*)S;
        float* e1 = (float*)(S + 16640);
        for (int t = tid; t < 4096; t += 512) {
            int o = t >> 6;
            int p = t & 63;
            out[(((size_t)(b * 64 + o)) << 14) + (i << 7) + j0 + p] =
                e0[o * 65 + p] + e1[o * 65 + p] + conv_b[o];
        }
    }
}

extern "C" void kernel_launch(void* const* d_in, const int* in_sizes, int n_in,
                              void* d_out, int out_size, void* d_ws, size_t ws_size,
                              hipStream_t stream) {
    const float* x = (const float*)d_in[0];
    const float* p_w = (const float*)d_in[1];
    const float* p_b = (const float*)d_in[2];
    const float* conv_w = (const float*)d_in[3];
    const float* conv_b = (const float*)d_in[4];
    float* out = (float*)d_out;
    char* ws = (char*)d_ws;

    unsigned short* x_t = (unsigned short*)(ws);
    unsigned short* cwtf = (unsigned short*)(ws + CWTF_OFF);
    unsigned short* pwtf = (unsigned short*)(ws + PWTF_OFF);

    k_prep<<<1240, 256, 0, stream>>>(x, (unsigned int*)x_t, conv_w, p_w, cwtf, pwtf);
    k_fused<<<1024, 512, 0, stream>>>(x_t, cwtf, pwtf, p_b, conv_b, out);
}

// Round 16
// 38.465 us; speedup vs baseline: 1.2348x; 1.1270x over previous
//
#include <hip/hip_runtime.h>
#include <math.h>

// B=4, C=64, H=W=128, OUTC=64, KS=3, taps N=9, K = 9*64 = 576. All fp16 data, f32 accum.
// ws layout (bytes):
//   x_t   fp16 [4][128][128][64]   @ 0        (8 MB) NHWC
//   cwtf  fp16 [9][2][4][64][8]    @ 8388608  (72 KB) main-conv B-fragments
//   pwtf  fp16 [9][2][2][64][8]    @ 8462336  (36 KB) offset-conv B-fragments (rows>=18 zero)
#define CWTF_OFF 8388608
#define PWTF_OFF (CWTF_OFF + 73728)

typedef __attribute__((ext_vector_type(8))) _Float16 half8;
typedef __attribute__((ext_vector_type(8))) unsigned short ushort8;
typedef __attribute__((ext_vector_type(4))) float f32x4;
typedef __attribute__((ext_vector_type(4))) unsigned int u32x4;

__device__ inline unsigned short f2h(float f) {
    _Float16 h = (_Float16)f; return __builtin_bit_cast(unsigned short, h);
}

// ---------------- prep: x NCHW f32 -> NHWC fp16, + weights -> fragment order (r11 version) ----------------
__global__ __launch_bounds__(256) void k_prep(const float* __restrict__ x,
                                              unsigned int* __restrict__ x_t_u32,
                                              const float* __restrict__ conv_w,
                                              const float* __restrict__ p_w,
                                              unsigned short* __restrict__ cwtf,
                                              unsigned short* __restrict__ pwtf) {
    if (blockIdx.x < 512) {
        __shared__ float t[64][129];
        int b = blockIdx.x >> 7;
        int i = blockIdx.x & 127;
        for (int idx = threadIdx.x; idx < 64 * 128; idx += 256) {
            int c = idx >> 7, j = idx & 127;
            t[c][j] = x[(((size_t)(b * 64 + c) * 128 + i) << 7) + j];
        }
        __syncthreads();
        unsigned int* dst = x_t_u32 + ((size_t)(b * 128 + i)) * 128 * 32;
        for (int idx2 = threadIdx.x; idx2 < 4096; idx2 += 256) {
            int j = idx2 >> 5, c2 = idx2 & 31;
            unsigned int lo = f2h(t[2 * c2][j]);
            unsigned int hi = f2h(t[2 * c2 + 1][j]);
            dst[idx2] = lo | (hi << 16);
        }
    } else {
        int tid = (blockIdx.x - 512) * 256 + threadIdx.x;
        if (tid < 36864) {
            int e = tid & 7, lane = (tid >> 3) & 63, nb = (tid >> 9) & 3, h = (tid >> 11) & 1, n = tid >> 12;
            int o = nb * 16 + (lane & 15);
            int c = h * 32 + ((lane >> 4) << 3) + e;
            cwtf[tid] = f2h(conv_w[(o * 64 + c) * 9 + n]);
        } else if (tid < 36864 + 18432) {
            int t2 = tid - 36864;
            int e = t2 & 7, lane = (t2 >> 3) & 63, nb = (t2 >> 9) & 1, h = (t2 >> 10) & 1, n = t2 >> 11;
            int np = nb * 16 + (lane & 15);
            int c = h * 32 + ((lane >> 4) << 3) + e;
            pwtf[t2] = (np < 18) ? f2h(p_w[(np * 64 + c) * 9 + n]) : (unsigned short)0;
        }
    }
}

// ---------------- fused kernel (r11 + baked pre-swizzled LDS offsets in geom) ----------------
// Block = 64 pixels (b, i, j0..j0+63), 8 waves (512 thr): wave wv = (pg = wv&3, h = wv>>2).
// Tile margin 3: covers |offset| < 2 (8 sigma) -> slow path statistically never taken.
// geom entry: hi16 = (rec*128 + ((rec&7)<<4)) >> 4 (pre-swizzled base), low16 = f16 weight.
// Phase-3 decode: addr = (hi<<4) ^ csx  (swizzle XOR commutes: bits 4-6 only).
// MFMA 16x16x32 f16: A m=lane&15, k=8*(lane>>4)+e; B n=lane&15 same k; D n=lane&15, m=4*(lane>>4)+reg.
#define TROWS 7
#define TCOLS 71
#define TRECS (TROWS * TCOLS)      // 497 records of 128 B (64 ch fp16)
#define TILE_B (TRECS * 128)       // 63616 B
#define OFF_OFFS TILE_B            // 4608 B  [64][18] f32 (stays live through phase 3 for fallback)
#define OFF_GEOM (TILE_B + 4608)   // 9216 B  [9][64][4] packed u32
#define OFF_FLAG (TILE_B + 4608 + 9216)
// Epilogue: ep0 @ 0, ep1 @ 16640 ([64][65] f32 each) overlay the dead tile.

__global__ __launch_bounds__(512, 2) void k_fused(const unsigned short* __restrict__ x_t,
                                                  const unsigned short* __restrict__ cwtf,
                                                  const unsigned short* __restrict__ pwtf,
                                                  const float* __restrict__ p_b,
                                                  const float* __restrict__ conv_b,
                                                  float* __restrict__ out) {
    __shared__ __align__(16) unsigned char S[TILE_B + 4608 + 9216 + 16];
    unsigned char* tile = S;
    float* offs = (float*)(S + OFF_OFFS);
    unsigned char* geomB = S + OFF_GEOM;
    int* flagp = (int*)(S + OFF_FLAG);

    int bid0 = blockIdx.x;
    int bid = (bid0 & 7) * 128 + (bid0 >> 3);  // chunked XCD swizzle (1024 % 8 == 0)
    int b = bid >> 8;
    int i = (bid >> 1) & 127;
    int j0 = (bid & 1) << 6;
    int ib = i - 3, jb = j0 - 3;

    int tid = threadIdx.x;
    int lane = tid & 63;
    int r15 = lane & 15;
    int g = lane >> 4;
    int wv = tid >> 6;
    int pg = wv & 3;
    int h = wv >> 2;
    int pl = pg * 16 + r15;      // this lane's A-row pixel
    int cs = g + (h << 2);       // chunk slot: channels cs*8..cs*8+7
    int csx = cs << 4;

    if (tid == 0) *flagp = 0;

    // ---- stage swizzled x-tile (coalesced global, swizzled ds_write) ----
    for (int u = tid; u < TRECS * 8; u += 512) {
        int rec = u >> 3, chunk = u & 7;
        int trow = rec / TCOLS;
        int tcol = rec - trow * TCOLS;
        int gr = ib + trow, gc = jb + tcol;
        bool v = ((unsigned)gr < 128u) && ((unsigned)gc < 128u);
        int grc = v ? gr : 0, gcc = v ? gc : 0;
        ushort8 val = *(const ushort8*)(x_t + (((size_t)((b * 128 + grc) * 128 + gcc)) << 6) + (chunk << 3));
        if (!v) val = (ushort8)(unsigned short)0;
        *(ushort8*)(tile + rec * 128 + ((chunk ^ (rec & 7)) << 4)) = val;
    }
    __syncthreads();

    // ---- phase 1: offset conv — wave supplies its channel-half's k-block ----
    f32x4 aco0 = (f32x4)0.f, aco1 = (f32x4)0.f;
    for (int n = 0; n < 9; ++n) {
        int du = n / 3 - 1, dv = n % 3 - 1;
        int trec = (du + 3) * TCOLS + (pl + dv + 3);
        int xb = trec & 7;
        half8 a = *(const half8*)(tile + trec * 128 + ((cs ^ xb) << 4));
        const unsigned short* pb = pwtf + (((n * 2 + h) * 2) << 9) + (lane << 3);
        half8 b0 = *(const half8*)pb;
        half8 b1 = *(const half8*)(pb + 512);
        aco0 = __builtin_amdgcn_mfma_f32_16x16x32_f16(a, b0, aco0, 0, 0, 0);
        aco1 = __builtin_amdgcn_mfma_f32_16x16x32_f16(a, b1, aco1, 0, 0, 0);
    }
    // cross-h reduction of offsets: h=0 writes (+bias), h=1 adds
#pragma unroll
    for (int hh = 0; hh < 2; ++hh) {
        if (h == hh) {
#pragma unroll
            for (int nb = 0; nb < 2; ++nb) {
                int np = nb * 16 + r15;
                if (np < 18) {
                    f32x4 a = nb ? aco1 : aco0;
#pragma unroll
                    for (int rr = 0; rr < 4; ++rr) {
                        int pix = pg * 16 + g * 4 + rr;
                        if (hh == 0)
                            offs[pix * 18 + np] = a[rr] + p_b[np];
                        else
                            offs[pix * 18 + np] += a[rr];
                    }
                }
            }
        }
        __syncthreads();
    }

    // ---- phase 2: bilinear geometry -> baked pre-swizzled LDS offsets ----
    for (int t = tid; t < 576; t += 512) {
        int p = t / 9;
        int n = t - p * 9;
        float ox = offs[p * 18 + n];
        float oy = offs[p * 18 + 9 + n];
        float px = ox + (float)(i + 1) + (float)(n / 3 - 1);
        float py = oy + (float)(j0 + p + 1) + (float)(n % 3 - 1);
        float fx = floorf(px), fy = floorf(py);
        float qlx = fminf(fmaxf(fx, 0.f), 129.f);
        float qrx = fminf(fmaxf(fx + 1.f, 0.f), 129.f);
        float qly = fminf(fmaxf(fy, 0.f), 129.f);
        float qry = fminf(fmaxf(fy + 1.f, 0.f), 129.f);
        float pxc = fminf(fmaxf(px, 0.f), 129.f);
        float pyc = fminf(fmaxf(py, 0.f), 129.f);
        float ax = 1.f + qlx - pxc;
        float bx = 1.f - qrx + pxc;
        float ay = 1.f + qly - pyc;
        float by = 1.f - qry + pyc;
        int rlx = (int)qlx - 1, rrx = (int)qrx - 1;
        int rly = (int)qly - 1, rry = (int)qry - 1;
        bool bad = false;
        unsigned int pk[4];
        int cx[4] = {rlx, rrx, rlx, rrx};
        int cy[4] = {rly, rry, rry, rly};
        float cw[4] = {ax * ay, bx * by, ax * by, bx * ay};
#pragma unroll
        for (int k = 0; k < 4; ++k) {
            bool v = ((unsigned)cx[k] < 128u) && ((unsigned)cy[k] < 128u);
            bool intile = (((unsigned)(cx[k] - ib) < (unsigned)TROWS) &&
                           ((unsigned)(cy[k] - jb) < (unsigned)TCOLS));
            unsigned rec = (unsigned)(cx[k] - ib) * TCOLS + (unsigned)(cy[k] - jb);
            // hi16 = pre-swizzled byte offset >> 4;  weight 0 for invalid (reads rec 0 harmlessly)
            pk[k] = (v && intile) ? (((rec * 8u + (rec & 7u)) << 16) | f2h(cw[k])) : 0u;
            bad = bad || (v && !intile);
        }
        *(u32x4*)(geomB + ((n * 64 + p) << 4)) = (u32x4){pk[0], pk[1], pk[2], pk[3]};
        if (bad) *flagp = 1;
    }
    __syncthreads();

    // ---- phase 3: main conv — 2-VALU corner decode, wave handles its k-half ----
    f32x4 acc[4];
#pragma unroll
    for (int nb = 0; nb < 4; ++nb) acc[nb] = (f32x4)0.f;
    bool fast = (*flagp == 0);

    if (fast) {
        for (int n = 0; n < 9; ++n) {
            u32x4 gq = *(const u32x4*)(geomB + ((n * 64 + pl) << 4));
            half8 Bf[4];
#pragma unroll
            for (int nb = 0; nb < 4; ++nb)
                Bf[nb] = *(const half8*)(cwtf + ((((n * 2 + h) << 2) + nb) << 9) + (lane << 3));
            half8 av = (half8)(_Float16)0;
#pragma unroll
            for (int k = 0; k < 4; ++k) {
                unsigned int p = gq[k];
                _Float16 wk = __builtin_bit_cast(_Float16, (unsigned short)(p & 0xFFFFu));
                half8 u = *(const half8*)(tile + (((p >> 16) << 4) ^ (unsigned)csx));
                av += u * wk;   // v_pk_fma_f16
            }
#pragma unroll
            for (int nb = 0; nb < 4; ++nb)
                acc[nb] = __builtin_amdgcn_mfma_f32_16x16x32_f16(av, Bf[nb], acc[nb], 0, 0, 0);
        }
    } else {
        // rare path: recompute geometry from offs (still live) per lane, gather from global
        for (int n = 0; n < 9; ++n) {
            half8 Bf[4];
#pragma unroll
            for (int nb = 0; nb < 4; ++nb)
                Bf[nb] = *(const half8*)(cwtf + ((((n * 2 + h) << 2) + nb) << 9) + (lane << 3));
            float ox = offs[pl * 18 + n];
            float oy = offs[pl * 18 + 9 + n];
            float px = ox + (float)(i + 1) + (float)(n / 3 - 1);
            float py = oy + (float)(j0 + pl + 1) + (float)(n % 3 - 1);
            float fx = floorf(px), fy = floorf(py);
            float qlx = fminf(fmaxf(fx, 0.f), 129.f);
            float qrx = fminf(fmaxf(fx + 1.f, 0.f), 129.f);
            float qly = fminf(fmaxf(fy, 0.f), 129.f);
            float qry = fminf(fmaxf(fy + 1.f, 0.f), 129.f);
            float pxc = fminf(fmaxf(px, 0.f), 129.f);
            float pyc = fminf(fmaxf(py, 0.f), 129.f);
            float ax = 1.f + qlx - pxc;
            float bx = 1.f - qrx + pxc;
            float ay = 1.f + qly - pyc;
            float by = 1.f - qry + pyc;
            int cx[4] = {(int)qlx - 1, (int)qrx - 1, (int)qlx - 1, (int)qrx - 1};
            int cy[4] = {(int)qly - 1, (int)qry - 1, (int)qry - 1, (int)qly - 1};
            float cw[4] = {ax * ay, bx * by, ax * by, bx * ay};
            half8 av = (half8)(_Float16)0;
#pragma unroll
            for (int k = 0; k < 4; ++k) {
                bool v = ((unsigned)cx[k] < 128u) && ((unsigned)cy[k] < 128u);
                size_t base = v ? (((size_t)((b * 128 + cx[k]) * 128 + cy[k])) << 6) : 0;
                _Float16 wk = v ? (_Float16)cw[k] : (_Float16)0.f;
                half8 u = *(const half8*)(x_t + base + (cs << 3));
                av += u * wk;
            }
#pragma unroll
            for (int nb = 0; nb < 4; ++nb)
                acc[nb] = __builtin_amdgcn_mfma_f32_16x16x32_f16(av, Bf[nb], acc[nb], 0, 0, 0);
        }
    }
    __syncthreads();  // tile dead; reuse as ep0/ep1

    // ---- epilogue: disjoint per-half regions, ONE barrier, summed at store ----
    {
        float* epH = (float*)(S + (h ? 16640 : 0));
#pragma unroll
        for (int nb = 0; nb < 4; ++nb) {
            int o = nb * 16 + r15;
#pragma unroll
            for (int rr = 0; rr < 4; ++rr) {
                int pix = pg * 16 + g * 4 + rr;
                epH[o * 65 + pix] = acc[nb][rr];
            }
        }
    }
    __syncthreads();
    {
        float* e0 = (float*)S;
        float* e1 = (float*)(S + 16640);
        for (int t = tid; t < 4096; t += 512) {
            int o = t >> 6;
            int p = t & 63;
            out[(((size_t)(b * 64 + o)) << 14) + (i << 7) + j0 + p] =
                e0[o * 65 + p] + e1[o * 65 + p] + conv_b[o];
        }
    }
}

extern "C" void kernel_launch(void* const* d_in, const int* in_sizes, int n_in,
                              void* d_out, int out_size, void* d_ws, size_t ws_size,
                              hipStream_t stream) {
    const float* x = (const float*)d_in[0];
    const float* p_w = (const float*)d_in[1];
    const float* p_b = (const float*)d_in[2];
    const float* conv_w = (const float*)d_in[3];
    const float* conv_b = (const float*)d_in[4];
    float* out = (float*)d_out;
    char* ws = (char*)d_ws;

    unsigned short* x_t = (unsigned short*)(ws);
    unsigned short* cwtf = (unsigned short*)(ws + CWTF_OFF);
    unsigned short* pwtf = (unsigned short*)(ws + PWTF_OFF);

    k_prep<<<728, 256, 0, stream>>>(x, (unsigned int*)x_t, conv_w, p_w, cwtf, pwtf);
    k_fused<<<1024, 512, 0, stream>>>(x_t, cwtf, pwtf, p_b, conv_b, out);
}